// Round 5
// baseline (1214.396 us; speedup 1.0000x reference)
//
#include <hip/hip_runtime.h>
#include <math.h>

#define NEG_INF (-3.402823466e+38f)

typedef __attribute__((ext_vector_type(8))) short short8;
typedef __attribute__((ext_vector_type(8))) unsigned short ushort8;
typedef __attribute__((ext_vector_type(4))) float f32x4;

// ---- dims ----
constexpr int NTOK = 4608;              // 2560 Q + 768 Wp + 256 Rp + 768 Wr + 256 Rr
constexpr int BH = 64 * 256;            // one (b,u) plane

// ---- static ws offsets (floats); ushort arrays use 2 elems per float slot ----
constexpr size_t OFF_WQ    = 0;                          // 524288
constexpr size_t OFF_B2    = OFF_WQ    + 524288;         // 2048
constexpr size_t OFF_XB3T  = OFF_B2    + 2048;           // 2048*960 us  = 983040 fl
constexpr size_t OFF_WB3T  = OFF_XB3T  + 983040;         // 512*1536 us  = 393216 fl
constexpr size_t OFF_L2B3T = OFF_WB3T  + 393216;         // 393216 fl
constexpr size_t OFF_C1B3T = OFF_L2B3T + 393216;         // 294912 fl
constexpr size_t OFF_C2B3T = OFF_C1B3T + 294912;         // 884736 fl
constexpr size_t OFF_C3B3T = OFF_C2B3T + 884736;         // 1474560 fl
constexpr size_t OFF_XHI   = OFF_C3B3T + 1474560;        // 737280 fl
constexpr size_t OFF_XLO   = OFF_XHI   + 737280;         // 737280 fl
constexpr size_t OFF_XP    = OFF_XLO   + 737280;         // 4608*2048 fp32 = 9437184
constexpr size_t OFF_HSQ   = OFF_XP    + 9437184;        // 1310720
constexpr size_t OFF_HSWP  = OFF_HSQ   + 1310720;        // 393216
constexpr size_t OFF_HSRP  = OFF_HSWP  + 393216;         // 131072
constexpr size_t OFF_HSWR  = OFF_HSRP  + 131072;         // 393216
constexpr size_t OFF_HSRR  = OFF_HSWR  + 393216;         // 131072
constexpr size_t OFF_RELP  = OFF_HSRR  + 131072;         // 524288
constexpr size_t OFF_RELC  = OFF_RELP  + 524288;         // 524288
constexpr size_t OFF_EN    = OFF_RELC  + 524288;         // 40960
// end = OFF_EN + 40960 = 19310592 fl (~77 MB; prior rounds used ~80 MB OK)
//
// XP-region aliases (XP dead after k_lstm); region = 9437184 fl:
//   QO1  +0        (1310720)   [dead after k_attsub]
//   RHI  +1310720  (524288)    RLO +1835008 (524288)   [dead after relw gemm]
//   RELW +2359296  (1048576)   [dead after energy_c]
//   Dhi  +3407872  (655360)    Dlo +4063232 (655360)   [dead after lin2]
//   QO2  +4718592  (1310720)   [live through k_attm2]
//   M2hi +0        (1313024)   M2lo +1313024 (1313024) [written by k_attm2]
//   Y    +2626048  (1474560 = Y1|Y2|Y3)

__device__ inline unsigned short f2bf(float f) {
  unsigned int u = __float_as_uint(f);
  u += 0x7FFFu + ((u >> 16) & 1u);          // RNE
  return (unsigned short)(u >> 16);
}
__device__ inline float bf2f(unsigned short h) {
  return __uint_as_float(((unsigned int)h) << 16);
}

// ================= prep: WQ + bias + all B3T (bf16-split, transposed, [hi|lo|hi]) ==========
__global__ __launch_bounds__(256) void k_prep(
    const float* __restrict__ Whh_f, const float* __restrict__ Whh_b,
    const float* __restrict__ b_f,   const float* __restrict__ b_b,
    const float* __restrict__ Wih_f, const float* __restrict__ Wih_b,
    const float* __restrict__ Wat,   const float* __restrict__ l2w,
    const float* __restrict__ c1w, const float* __restrict__ c2w, const float* __restrict__ c3w,
    float* __restrict__ WQ, float* __restrict__ B2,
    unsigned short* __restrict__ XB3T, unsigned short* __restrict__ WB3T,
    unsigned short* __restrict__ L2B3T,
    unsigned short* __restrict__ C1B3T, unsigned short* __restrict__ C2B3T,
    unsigned short* __restrict__ C3B3T) {
  int idx = blockIdx.x * 256 + threadIdx.x;
  if (idx < 524288) {                       // WQ[d][k4][g][u][kk]
    int d = idx >> 18, l = idx & 262143;
    int kk = l & 3, u = (l >> 2) & 255, g = (l >> 10) & 3, k4 = l >> 12;
    const float* Wh = d ? Whh_b : Whh_f;
    WQ[idx] = Wh[(size_t)(g*256 + u)*256 + k4*4 + kk];
    return;
  }
  idx -= 524288;
  if (idx < 2048) { B2[idx] = (idx < 1024) ? b_f[idx] : b_b[idx-1024]; return; }
  idx -= 2048;
  unsigned short* dst; int n, k, K;
  float w;
  if (idx < 655360) {                       // XB3T: n<2048, Kp=320 (src K=300)
    n = idx / 320; k = idx % 320; K = 320; dst = XB3T;
    w = (k < 300) ? ((n < 1024) ? Wih_f[(size_t)n*300 + k] : Wih_b[(size_t)(n-1024)*300 + k]) : 0.f;
  } else if ((idx -= 655360) < 262144) {    // WB3T: B[k][n] = Wat[k][n]
    n = idx >> 9; k = idx & 511; K = 512; dst = WB3T;
    w = Wat[(size_t)k*512 + n];
  } else if ((idx -= 262144) < 262144) {    // L2B3T: B[k][n] = l2w[n][k]
    n = idx >> 9; k = idx & 511; K = 512; dst = L2B3T;
    w = l2w[(size_t)n*512 + k];
  } else if ((idx -= 262144) < 196608) {    // C1B3T (n pad 192)
    n = idx >> 10; k = idx & 1023; K = 1024; dst = C1B3T;
    w = (n < 150) ? c1w[(size_t)n*1024 + k] : 0.f;
  } else if ((idx -= 196608) < 589824) {    // C2B3T
    n = idx / 3072; k = idx % 3072; K = 3072; dst = C2B3T;
    int kw = k >> 10, c = k & 1023;
    w = (n < 150) ? c2w[((size_t)n*1024 + c)*3 + kw] : 0.f;
  } else if ((idx -= 589824) < 983040) {    // C3B3T
    n = idx / 5120; k = idx % 5120; K = 5120; dst = C3B3T;
    int kw = k >> 10, c = k & 1023;
    w = (n < 150) ? c3w[((size_t)n*1024 + c)*5 + kw] : 0.f;
  } else return;
  unsigned short hi = f2bf(w);
  unsigned short lo = f2bf(w - bf2f(hi));
  size_t base = (size_t)n * (3*K);
  dst[base + k] = hi;
  dst[base + K + k] = lo;
  dst[base + 2*K + k] = hi;
}

// ================= gather embeddings -> bf16 split, K padded to 320 =================
__global__ __launch_bounds__(320) void k_gather(
    const int* __restrict__ q,  const int* __restrict__ wr, const int* __restrict__ rr,
    const int* __restrict__ wp, const int* __restrict__ rp,
    const float* __restrict__ we, const float* __restrict__ re,
    unsigned short* __restrict__ Xhi, unsigned short* __restrict__ Xlo) {
  int m = blockIdx.x, k = threadIdx.x;
  const float* emb; int row;
  if (m < 2560)      { int t=m>>6,    b=m&63; row = q [b*40+t]; emb = we; }
  else if (m < 3328) { int mm=m-2560; int t=mm>>6,b=mm&63; row = wp[b*12+t]; emb = we; }
  else if (m < 3584) { int mm=m-3328; int t=mm>>6,b=mm&63; row = rp[b*4 +t]; emb = re; }
  else if (m < 4352) { int mm=m-3584; int t=mm>>6,b=mm&63; row = wr[b*12+t]; emb = we; }
  else               { int mm=m-4352; int t=mm>>6,b=mm&63; row = rr[b*4 +t]; emb = re; }
  float v = (k < 300) ? emb[(size_t)row*300 + k] : 0.f;
  unsigned short hi = f2bf(v);
  Xhi[(size_t)m*320 + k] = hi;
  Xlo[(size_t)m*320 + k] = f2bf(v - bf2f(hi));
}

// ===== MFMA GEMM (bf16 3-split): C[M][N] = sum over 3K of Asel[m][kk] * Bt[n][k0] =====
template<bool BIAS>
__global__ __launch_bounds__(256) void k_mgemm(
    const unsigned short* __restrict__ Ahi, const unsigned short* __restrict__ Alo, int lda,
    const unsigned short* __restrict__ Bt, const float* __restrict__ bias,
    float* __restrict__ C, int N, int K) {
  __shared__ unsigned short As[64 * 40];   // rows padded to 40 ushorts
  __shared__ unsigned short Bs[64 * 40];
  int tid = threadIdx.x;
  int wave = tid >> 6, lane = tid & 63;
  int quad = lane >> 4, l16 = lane & 15;
  int m0 = blockIdx.x << 6, n0 = blockIdx.y << 6;
  int K3 = 3 * K;
  int sr = tid >> 2;
  int sc = (tid & 3) << 3;
  f32x4 acc[4] = {};
  for (int k0 = 0; k0 < K3; k0 += 32) {
    int c = (k0 >= K) + (k0 >= 2*K);
    const unsigned short* Asrc = (c == 2) ? Alo : Ahi;
    int kk = k0 - c * K;
    ushort8 av = *(const ushort8*)(Asrc + (size_t)(m0 + sr) * lda + kk + sc);
    ushort8 bv = *(const ushort8*)(Bt + (size_t)(n0 + sr) * K3 + k0 + sc);
    *(ushort8*)&As[sr * 40 + sc] = av;
    *(ushort8*)&Bs[sr * 40 + sc] = bv;
    __syncthreads();
    short8 a  = *(const short8*)&As[(wave*16 + l16) * 40 + quad*8];
    short8 b0 = *(const short8*)&Bs[( 0 + l16) * 40 + quad*8];
    short8 b1 = *(const short8*)&Bs[(16 + l16) * 40 + quad*8];
    short8 b2 = *(const short8*)&Bs[(32 + l16) * 40 + quad*8];
    short8 b3 = *(const short8*)&Bs[(48 + l16) * 40 + quad*8];
    acc[0] = __builtin_amdgcn_mfma_f32_16x16x32_bf16(a, b0, acc[0], 0, 0, 0);
    acc[1] = __builtin_amdgcn_mfma_f32_16x16x32_bf16(a, b1, acc[1], 0, 0, 0);
    acc[2] = __builtin_amdgcn_mfma_f32_16x16x32_bf16(a, b2, acc[2], 0, 0, 0);
    acc[3] = __builtin_amdgcn_mfma_f32_16x16x32_bf16(a, b3, acc[3], 0, 0, 0);
    __syncthreads();
  }
  int row0 = m0 + wave * 16 + quad * 4;
#pragma unroll
  for (int t = 0; t < 4; t++) {
    int col = n0 + t * 16 + l16;
    float bb = BIAS ? bias[col] : 0.f;
#pragma unroll
    for (int r = 0; r < 4; r++)
      C[(size_t)(row0 + r) * N + col] = acc[t][r] + bb;
  }
}

// ===== fused conv GEMMs, split-K, atomic accumulate into zeroed Y =====
__global__ __launch_bounds__(256) void k_cgemm(
    const unsigned short* __restrict__ Ahi, const unsigned short* __restrict__ Alo,
    const unsigned short* __restrict__ B1, const unsigned short* __restrict__ B2c,
    const unsigned short* __restrict__ B3,
    float* __restrict__ Y1, float* __restrict__ Y2, float* __restrict__ Y3) {
  __shared__ unsigned short As[64 * 40];
  __shared__ unsigned short Bs[64 * 40];
  int z = blockIdx.z;
  const unsigned short* Bt; float* Y; int K, sidx, chunk;
  if (z < 4)       { Bt = B1;  Y = Y1; K = 1024; sidx = z;      chunk = 768;  }
  else if (z < 12) { Bt = B2c; Y = Y2; K = 3072; sidx = z - 4;  chunk = 1152; }
  else             { Bt = B3;  Y = Y3; K = 5120; sidx = z - 12; chunk = 1920; }
  int K3 = 3 * K;
  int ks = sidx * chunk, ke = ks + chunk;
  int tid = threadIdx.x;
  int wave = tid >> 6, lane = tid & 63;
  int quad = lane >> 4, l16 = lane & 15;
  int m0 = blockIdx.x << 6, n0 = blockIdx.y << 6;
  int sr = tid >> 2;
  int sc = (tid & 3) << 3;
  f32x4 acc[4] = {};
  for (int k0 = ks; k0 < ke; k0 += 32) {
    int c = (k0 >= K) + (k0 >= 2*K);
    const unsigned short* Asrc = (c == 2) ? Alo : Ahi;
    int kk = k0 - c * K;
    ushort8 av = *(const ushort8*)(Asrc + (size_t)(m0 + sr) * 1024 + kk + sc);
    ushort8 bv = *(const ushort8*)(Bt + (size_t)(n0 + sr) * K3 + k0 + sc);
    *(ushort8*)&As[sr * 40 + sc] = av;
    *(ushort8*)&Bs[sr * 40 + sc] = bv;
    __syncthreads();
    short8 a  = *(const short8*)&As[(wave*16 + l16) * 40 + quad*8];
    short8 b0 = *(const short8*)&Bs[( 0 + l16) * 40 + quad*8];
    short8 b1 = *(const short8*)&Bs[(16 + l16) * 40 + quad*8];
    short8 b2 = *(const short8*)&Bs[(32 + l16) * 40 + quad*8];
    short8 b3 = *(const short8*)&Bs[(48 + l16) * 40 + quad*8];
    acc[0] = __builtin_amdgcn_mfma_f32_16x16x32_bf16(a, b0, acc[0], 0, 0, 0);
    acc[1] = __builtin_amdgcn_mfma_f32_16x16x32_bf16(a, b1, acc[1], 0, 0, 0);
    acc[2] = __builtin_amdgcn_mfma_f32_16x16x32_bf16(a, b2, acc[2], 0, 0, 0);
    acc[3] = __builtin_amdgcn_mfma_f32_16x16x32_bf16(a, b3, acc[3], 0, 0, 0);
    __syncthreads();
  }
  int row0 = m0 + wave * 16 + quad * 4;
#pragma unroll
  for (int t = 0; t < 4; t++) {
    int col = n0 + t * 16 + l16;
#pragma unroll
    for (int r = 0; r < 4; r++)
      atomicAdd(&Y[(size_t)(row0 + r) * 192 + col], acc[t][r]);
  }
}

// ===== whole recurrence in ONE kernel: block-private (slot, batch-group) state ======
// slot=blockIdx.y: si=slot>>1 (0:Q 40 steps; 1:Wp->Rp 16; 2:Wr->Rr 16), dir=slot&1.
// h ping-pongs in LDS; c lives in registers; (h,c) carry across the Wp->Rp transition
// inside the same block (this is why the word->rela initial-state handoff is free).
template<int BB>
__global__ __launch_bounds__(256) void k_lstm(
    const float* __restrict__ WQ, const float* __restrict__ XP,
    float* __restrict__ hsQ, float* __restrict__ hsWp, float* __restrict__ hsRp,
    float* __restrict__ hsWr, float* __restrict__ hsRr) {
  int slot = blockIdx.y;
  int dir = slot & 1, si = slot >> 1;
  int b0 = blockIdx.x * BB;
  int u = threadIdx.x;
  __shared__ float hl[2][BB][260];
  for (int i = threadIdx.x; i < BB * 256; i += 256) hl[0][i >> 8][i & 255] = 0.f;
  __syncthreads();
  float cst[BB];
#pragma unroll
  for (int b = 0; b < BB; b++) cst[b] = 0.f;
  const float* wb = WQ + (size_t)dir * 262144 + u * 4;
  int nsteps = (si == 0) ? 40 : 16;
  for (int step = 0; step < nsteps; ++step) {
    int t, T, seg; float* hsb;
    if (si == 0)       { t = step;      T = 40; seg = 0;
                         hsb = hsQ + (size_t)dir * 40 * BH; }
    else if (step < 12){ t = step;      T = 12; seg = (si == 1) ? 2560 : 3584;
                         hsb = ((si == 1) ? hsWp : hsWr) + (size_t)dir * 12 * BH; }
    else               { t = step - 12; T = 4;  seg = (si == 1) ? 3328 : 4352;
                         hsb = ((si == 1) ? hsRp : hsRr) + (size_t)dir * 4 * BH; }
    int cur = step & 1, nxt = cur ^ 1;

    float acc[4][BB];
#pragma unroll
    for (int g = 0; g < 4; g++)
#pragma unroll
      for (int b = 0; b < BB; b++) acc[g][b] = 0.f;

#pragma unroll 2
    for (int k4 = 0; k4 < 64; k4++) {
      float4 w0 = *(const float4*)(wb + k4*4096);
      float4 w1 = *(const float4*)(wb + k4*4096 + 1024);
      float4 w2 = *(const float4*)(wb + k4*4096 + 2048);
      float4 w3 = *(const float4*)(wb + k4*4096 + 3072);
#pragma unroll
      for (int b = 0; b < BB; b++) {
        float4 h4 = *(const float4*)&hl[cur][b][k4*4];
        acc[0][b] += w0.x*h4.x + w0.y*h4.y + w0.z*h4.z + w0.w*h4.w;
        acc[1][b] += w1.x*h4.x + w1.y*h4.y + w1.z*h4.z + w1.w*h4.w;
        acc[2][b] += w2.x*h4.x + w2.y*h4.y + w2.z*h4.z + w2.w*h4.w;
        acc[3][b] += w3.x*h4.x + w3.y*h4.y + w3.z*h4.z + w3.w*h4.w;
      }
    }

    int t_in = dir ? (T - 1 - t) : t;
#pragma unroll
    for (int b = 0; b < BB; b++) {
      const float* xr = XP + (size_t)(seg + t_in*64 + b0 + b) * 2048 + dir*1024 + u;
      float zi = acc[0][b] + xr[0];
      float zf = acc[1][b] + xr[256];
      float zg = acc[2][b] + xr[512];
      float zo = acc[3][b] + xr[768];
      float gi = 1.f / (1.f + expf(-zi));
      float gf = 1.f / (1.f + expf(-zf));
      float go = 1.f / (1.f + expf(-zo));
      float gg = tanhf(zg);
      float cn = gf * cst[b] + gi * gg;
      float hn = go * tanhf(cn);
      cst[b] = cn;
      hl[nxt][b][u] = hn;
      hsb[(size_t)t * BH + (b0 + b) * 256 + u] = hn;
    }
    __syncthreads();
  }
}

// ================= reshape: QO1[b][s][h] + REL tensors (fp32 + packed bf16 splits) =======
__global__ __launch_bounds__(256) void k_reshape(
    const float* __restrict__ hsQ,
    const float* __restrict__ hsWp, const float* __restrict__ hsRp,
    const float* __restrict__ hsWr, const float* __restrict__ hsRr,
    float* __restrict__ QT,
    float* __restrict__ RELP, float* __restrict__ RELC,
    unsigned short* __restrict__ RHI, unsigned short* __restrict__ RLO) {
  int idx0 = blockIdx.x * 256 + threadIdx.x;
  if (idx0 < 1310720) {                       // QO1
    int idx = idx0;
    int h = idx & 511; int t2 = idx >> 9; int s = t2 % 40; int b = t2 / 40;
    float v;
    if (h < 256) v = hsQ[(size_t)s * BH + b*256 + h];
    else         v = hsQ[(size_t)40 * BH + (size_t)(39 - s) * BH + b*256 + (h - 256)];
    QT[idx] = v;
    return;
  }
  idx0 -= 1310720;
  if (idx0 >= 2*64*16*512) return;
  int call = idx0 >= 64*16*512;
  int idx = idx0 - call * 64*16*512;
  int h = idx & 511; int t2 = idx >> 9; int r = t2 & 15; int b = t2 >> 4;
  const float* hsW = call ? hsWr : hsWp;
  const float* hsR = call ? hsRr : hsRp;
  float v;
  if (r < 4) {
    if (h < 256) v = hsR[(size_t)r * BH + b*256 + h];
    else         v = hsR[(size_t)4 * BH + (size_t)(3 - r) * BH + b*256 + (h - 256)];
  } else {
    int t = r - 4;
    if (h < 256) v = hsW[(size_t)t * BH + b*256 + h];
    else         v = hsW[(size_t)12 * BH + (size_t)(11 - t) * BH + b*256 + (h - 256)];
  }
  unsigned short hi = f2bf(v);
  unsigned short lo = f2bf(v - bf2f(hi));
  (call ? RELC : RELP)[idx] = v;
  RHI[(size_t)call * 524288 + idx] = hi;
  RLO[(size_t)call * 524288 + idx] = lo;
}

// ================= energy[b][r][s] =================
__global__ __launch_bounds__(256) void k_energy(
    const float* __restrict__ relW, const float* __restrict__ QT, float* __restrict__ EN) {
  int idx = blockIdx.x * 256 + threadIdx.x;
  if (idx >= 64*16*40) return;
  int s = idx % 40; int t = idx / 40; int r = t & 15; int b = t >> 4;
  const float* rw = relW + (size_t)(b*16 + r) * 512;
  const float* qv = QT   + (size_t)(b*40 + s) * 512;
  float acc = 0.f;
#pragma unroll 4
  for (int k = 0; k < 512; k += 4) {
    float4 a = *(const float4*)(rw + k);
    float4 c = *(const float4*)(qv + k);
    acc += a.x*c.x + a.y*c.y + a.z*c.z + a.w*c.w;
  }
  EN[idx] = acc;
}

// ================= softmax over 640 per b =================
__global__ __launch_bounds__(256) void k_softmax(float* __restrict__ EN) {
  int b = blockIdx.x; int tid = threadIdx.x;
  float* e = EN + b * 640;
  float v0 = e[tid] * 0.25f, v1 = e[tid + 256] * 0.25f;
  float v2 = (tid < 128) ? e[tid + 512] * 0.25f : NEG_INF;
  __shared__ float sh[256];
  sh[tid] = fmaxf(v0, fmaxf(v1, v2));
  __syncthreads();
  for (int st = 128; st > 0; st >>= 1) { if (tid < st) sh[tid] = fmaxf(sh[tid], sh[tid+st]); __syncthreads(); }
  float m = sh[0];
  __syncthreads();
  float e0 = expf(v0 - m), e1 = expf(v1 - m);
  float e2 = (tid < 128) ? expf(v2 - m) : 0.f;
  sh[tid] = e0 + e1 + e2;
  __syncthreads();
  for (int st = 128; st > 0; st >>= 1) { if (tid < st) sh[tid] += sh[tid+st]; __syncthreads(); }
  float inv = 1.f / sh[0];
  e[tid] = e0 * inv; e[tid + 256] = e1 * inv;
  if (tid < 128) e[tid + 512] = e2 * inv;
}

// ===== fused atten+sub (prev): D = QO1 - atten, bf16-split out =====
__global__ __launch_bounds__(256) void k_attsub(
    const float* __restrict__ AL, const float* __restrict__ REL,
    const float* __restrict__ QT,
    unsigned short* __restrict__ Dhi, unsigned short* __restrict__ Dlo) {
  int idx = blockIdx.x * 256 + threadIdx.x;
  if (idx >= 64*40*512) return;
  int h = idx & 511; int t2 = idx >> 9; int s = t2 % 40; int b = t2 / 40;
  const float* al = AL + b * 640 + s;
  const float* rl = REL + (size_t)b * 16 * 512 + h;
  float acc = 0.f;
#pragma unroll
  for (int r = 0; r < 16; r++) acc += al[r*40] * rl[r*512];
  float v = QT[idx] - acc;
  unsigned short hi = f2bf(v);
  Dhi[idx] = hi; Dlo[idx] = f2bf(v - bf2f(hi));
}

// ===== fused atten(curr)+M2 pack (+Y zero in tail blocks) =====
__global__ __launch_bounds__(256) void k_attm2(
    const float* __restrict__ AL, const float* __restrict__ REL,
    const float* __restrict__ QO2,
    unsigned short* __restrict__ M2hi, unsigned short* __restrict__ M2lo,
    float* __restrict__ Yz) {
  int idx = blockIdx.x * 256 + threadIdx.x;
  if (idx < 2626048) {
    float v = 0.f;
    int c = idx & 1023; int m = idx >> 10;
    if (m < 2560) {
      if (c < 512) v = QO2[(size_t)m*512 + c];
      else {
        int b = m / 40, s = m % 40, h = c - 512;
        const float* al = AL + b * 640 + s;
        const float* rl = REL + (size_t)b * 16 * 512 + h;
        float acc = 0.f;
#pragma unroll
        for (int r = 0; r < 16; r++) acc += al[r*40] * rl[r*512];
        v = acc;
      }
    }
    unsigned short hi = f2bf(v);
    M2hi[idx] = hi; M2lo[idx] = f2bf(v - bf2f(hi));
    return;
  }
  int z = idx - 2626048;
  if (z < 368640) *(float4*)(Yz + (size_t)z * 4) = make_float4(0.f, 0.f, 0.f, 0.f);
}

// ================= pool(bias+relu+max over l) + score =================
__global__ __launch_bounds__(256) void k_pool(
    const float* __restrict__ Y1, const float* __restrict__ Y2, const float* __restrict__ Y3,
    const float* __restrict__ b1, const float* __restrict__ b2, const float* __restrict__ b3,
    const float* __restrict__ lw, float* __restrict__ out) {
  int b = blockIdx.x, o = threadIdx.x;
  float hv = 0.f;
  if (o < 150) {
    const float* y1 = Y1 + (size_t)b*40*192 + o;
    const float* y2 = Y2 + (size_t)b*40*192 + o;
    const float* y3 = Y3 + (size_t)b*40*192 + o;
    float m1 = NEG_INF, m2 = NEG_INF, m3 = NEG_INF;
#pragma unroll 4
    for (int l = 0; l < 40; l++) m1 = fmaxf(m1, y1[l*192]);
#pragma unroll 2
    for (int l = 0; l < 38; l++) m2 = fmaxf(m2, y2[l*192]);
#pragma unroll 2
    for (int l = 0; l < 36; l++) m3 = fmaxf(m3, y3[l*192]);
    float h = fmaxf(fmaxf(m1 + b1[o], m2 + b2[o]), m3 + b3[o]);
    hv = fmaxf(h, 0.f) * lw[o];
  }
  __shared__ float sh[256];
  sh[threadIdx.x] = hv;
  __syncthreads();
  for (int st = 128; st > 0; st >>= 1) { if (threadIdx.x < st) sh[threadIdx.x] += sh[threadIdx.x+st]; __syncthreads(); }
  if (threadIdx.x == 0) out[b] = sh[0];
}

// ================= host =================
extern "C" void kernel_launch(void* const* d_in, const int* in_sizes, int n_in,
                              void* d_out, int out_size, void* d_ws, size_t ws_size,
                              hipStream_t stream) {
  const int*   q    = (const int*)d_in[0];
  const int*   wrel = (const int*)d_in[1];
  const int*   rrel = (const int*)d_in[2];
  const int*   wprv = (const int*)d_in[3];
  const int*   rprv = (const int*)d_in[4];
  const float* we   = (const float*)d_in[5];
  const float* re   = (const float*)d_in[6];
  const float* Wih_f= (const float*)d_in[7];
  const float* Whh_f= (const float*)d_in[8];
  const float* b_f  = (const float*)d_in[9];
  const float* Wih_b= (const float*)d_in[10];
  const float* Whh_b= (const float*)d_in[11];
  const float* b_b  = (const float*)d_in[12];
  const float* W    = (const float*)d_in[13];
  const float* c1w  = (const float*)d_in[14];
  const float* c1b  = (const float*)d_in[15];
  const float* c2w  = (const float*)d_in[16];
  const float* c2b  = (const float*)d_in[17];
  const float* c3w  = (const float*)d_in[18];
  const float* c3b  = (const float*)d_in[19];
  const float* lw   = (const float*)d_in[20];
  const float* l2w  = (const float*)d_in[21];
  const float* l2b  = (const float*)d_in[22];
  float* out = (float*)d_out;
  float* ws  = (float*)d_ws;

  float* WQk  = ws + OFF_WQ;
  float* B2   = ws + OFF_B2;
  unsigned short* XB3T  = (unsigned short*)(ws + OFF_XB3T);
  unsigned short* WB3T  = (unsigned short*)(ws + OFF_WB3T);
  unsigned short* L2B3T = (unsigned short*)(ws + OFF_L2B3T);
  unsigned short* C1B3T = (unsigned short*)(ws + OFF_C1B3T);
  unsigned short* C2B3T = (unsigned short*)(ws + OFF_C2B3T);
  unsigned short* C3B3T = (unsigned short*)(ws + OFF_C3B3T);
  unsigned short* Xhi   = (unsigned short*)(ws + OFF_XHI);
  unsigned short* Xlo   = (unsigned short*)(ws + OFF_XLO);
  float* XP   = ws + OFF_XP;
  float* HSQ  = ws + OFF_HSQ;
  float* HSWP = ws + OFF_HSWP;
  float* HSRP = ws + OFF_HSRP;
  float* HSWR = ws + OFF_HSWR;
  float* HSRR = ws + OFF_HSRR;
  float* RELP = ws + OFF_RELP;
  float* RELC = ws + OFF_RELC;
  float* EN   = ws + OFF_EN;
  // XP-region aliases (XP dead after k_lstm)
  float* QO1  = XP;
  unsigned short* RHI = (unsigned short*)(XP + 1310720);
  unsigned short* RLO = (unsigned short*)(XP + 1835008);
  float* RELW = XP + 2359296;              // 2048 x 512: prev rows 0..1023, curr 1024..2047
  unsigned short* Dhi = (unsigned short*)(XP + 3407872);
  unsigned short* Dlo = (unsigned short*)(XP + 4063232);
  float* QO2  = XP + 4718592;
  unsigned short* M2hi = (unsigned short*)(XP);            // QO1 dead by then
  unsigned short* M2lo = (unsigned short*)(XP + 1313024);
  float* Yall = XP + 2626048;              // 3 x 491520 contiguous
  float* Y1   = Yall;
  float* Y2   = Yall + 491520;
  float* Y3   = Yall + 983040;

  k_prep<<<13576, 256, 0, stream>>>(Whh_f, Whh_b, b_f, b_b, Wih_f, Wih_b, W, l2w,
                                    c1w, c2w, c3w,
                                    WQk, B2, XB3T, WB3T, L2B3T, C1B3T, C2B3T, C3B3T);
  k_gather<<<NTOK, 320, 0, stream>>>(q, wrel, rrel, wprv, rprv, we, re, Xhi, Xlo);
  { dim3 g(72, 32); k_mgemm<true><<<g, 256, 0, stream>>>(Xhi, Xlo, 320, XB3T, B2, XP, 2048, 320); }

  // whole recurrence, ONE launch
  { dim3 g(16, 6); k_lstm<4><<<g, 256, 0, stream>>>(WQk, XP, HSQ, HSWP, HSRP, HSWR, HSRR); }

  k_reshape<<<9216, 256, 0, stream>>>(HSQ, HSWP, HSRP, HSWR, HSRR,
                                      QO1, RELP, RELC, RHI, RLO);

  // both relation*W GEMMs in one launch (M=2048)
  { dim3 g(32, 8); k_mgemm<false><<<g, 256, 0, stream>>>(RHI, RLO, 512, WB3T, nullptr, RELW, 512, 512); }

  // ---- attention (previous hop) ----
  k_energy<<<160, 256, 0, stream>>>(RELW, QO1, EN);
  k_softmax<<<64, 256, 0, stream>>>(EN);
  k_attsub<<<5120, 256, 0, stream>>>(EN, RELP, QO1, Dhi, Dlo);
  { dim3 g(40, 8); k_mgemm<true><<<g, 256, 0, stream>>>(Dhi, Dlo, 512, L2B3T, l2b, QO2, 512, 512); }

  // ---- attention (current relation) ----
  k_energy<<<160, 256, 0, stream>>>(RELW + (size_t)1024*512, QO2, EN);
  k_softmax<<<64, 256, 0, stream>>>(EN);
  k_attm2<<<11698, 256, 0, stream>>>(EN, RELC, QO2, M2hi, M2lo, Yall);

  // ---- convs: fused split-K MFMA GEMM, atomic accumulate ----
  { dim3 g(40, 3, 20); k_cgemm<<<g, 256, 0, stream>>>(M2hi, M2lo, C1B3T, C2B3T, C3B3T, Y1, Y2, Y3); }
  k_pool<<<64, 256, 0, stream>>>(Y1, Y2, Y3, c1b, c2b, c3b, lw, out);
}